// Round 1
// baseline (12.363 us; speedup 1.0000x reference)
//
#include <hip/hip_runtime.h>
#include <math.h>

// Single-thread computation of:
//   T = Ttrans @ T1inv @ T2inv @ T3inv @ T4b3 @ T4b2 @ T4b1 @ T4a @ T3 @ T2 @ T1
//   new_header = T @ header
//   affine = (inv(new_header) @ vol_affine)[:3]
// Output layout: affine (12 f32) then new_header (16 f32), flat, return order.
// All math in f64 (reference is numpy); ~1.5 kFLOP -> launch-overhead bound.

__device__ inline void matmul4(const double* A, const double* B, double* C) {
    for (int i = 0; i < 4; ++i)
        for (int j = 0; j < 4; ++j) {
            double s = 0.0;
            for (int k = 0; k < 4; ++k) s += A[i*4+k] * B[k*4+j];
            C[i*4+j] = s;
        }
}

__device__ inline void eye4(double* M) {
    for (int i = 0; i < 16; ++i) M[i] = 0.0;
    M[0] = M[5] = M[10] = M[15] = 1.0;
}

__global__ void affine_kernel(const float* __restrict__ header,
                              const float* __restrict__ vol_affine,
                              const float* __restrict__ cr,
                              const float* __restrict__ normvec,
                              const float* __restrict__ translation,
                              const float* __restrict__ angle,
                              const float* __restrict__ scaling,
                              float* __restrict__ out) {
    if (threadIdx.x != 0 || blockIdx.x != 0) return;

    const double PI = 3.14159265358979323846;

    // nv = normvec / ||normvec||
    double n0 = (double)normvec[0], n1 = (double)normvec[1], n2 = (double)normvec[2];
    double nn = sqrt(n0 * n0 + n1 * n1 + n2 * n2);
    double nv0 = n0 / nn, nv1 = n1 / nn, nv2 = n2 / nn;
    double norm_xy = sqrt(nv0 * nv0 + nv1 * nv1);

    bool zero_xy = (norm_xy == 0.0);
    double safe = zero_xy ? 1.0 : norm_xy;
    double a = zero_xy ? 1.0 : nv0 / safe;
    double b = zero_xy ? 0.0 : nv1 / safe;

    double T1[16], T1inv[16], T2[16], T2inv[16], T3[16], T3inv[16];
    double T4a[16], T4b1[16], T4b2[16], T4b3[16], Ttrans[16];

    eye4(T1);    T1[3]   = -(double)cr[0]; T1[7]   = -(double)cr[1]; T1[11]   = -(double)cr[2];
    eye4(T1inv); T1inv[3] = (double)cr[0]; T1inv[7] = (double)cr[1]; T1inv[11] = (double)cr[2];

    eye4(T2);    T2[0] = a;    T2[1] = b;     T2[4] = -b;    T2[5] = a;
    eye4(T2inv); T2inv[0] = a; T2inv[1] = -b; T2inv[4] = b;  T2inv[5] = a;

    eye4(T3);    T3[0] = nv2;    T3[2] = -norm_xy;    T3[8] = norm_xy;     T3[10] = nv2;
    eye4(T3inv); T3inv[0] = nv2; T3inv[2] = norm_xy;  T3inv[8] = -norm_xy; T3inv[10] = nv2;

    double sxy = exp((double)scaling[0] / 100.0);
    double sz  = exp((double)scaling[1] / 100.0);
    eye4(T4a); T4a[0] = sxy; T4a[5] = sxy; T4a[10] = sz;

    double a0 = (double)angle[0] / 180.0 * PI;
    double a1 = (double)angle[1] / 180.0 * PI;
    double a2 = (double)angle[2] / 180.0 * PI;
    double c0 = cos(a0), s0 = sin(a0);
    double c1 = cos(a1), s1 = sin(a1);
    double c2 = cos(a2), s2 = sin(a2);
    eye4(T4b1); T4b1[5] = c0; T4b1[6] = -s0; T4b1[9] = s0;  T4b1[10] = c0;
    eye4(T4b2); T4b2[0] = c1; T4b2[2] = s1;  T4b2[8] = -s1; T4b2[10] = c1;
    eye4(T4b3); T4b3[0] = c2; T4b3[1] = -s2; T4b3[4] = s2;  T4b3[5] = c2;

    eye4(Ttrans);
    Ttrans[3]  = (double)translation[0];
    Ttrans[7]  = (double)translation[1];
    Ttrans[11] = (double)translation[2];

    // T = Ttrans @ T1inv @ T2inv @ T3inv @ T4b3 @ T4b2 @ T4b1 @ T4a @ T3 @ T2 @ T1
    double acc[16], tmp[16];
    matmul4(Ttrans, T1inv, acc);
    matmul4(acc, T2inv, tmp);
    matmul4(tmp, T3inv, acc);
    matmul4(acc, T4b3, tmp);
    matmul4(tmp, T4b2, acc);
    matmul4(acc, T4b1, tmp);
    matmul4(tmp, T4a, acc);
    matmul4(acc, T3, tmp);
    matmul4(tmp, T2, acc);
    matmul4(acc, T1, tmp);   // tmp = T

    // new_header = T @ header
    double H[16];
    for (int i = 0; i < 16; ++i) H[i] = (double)header[i];
    double NH[16];
    matmul4(tmp, H, NH);

    // inv(new_header) via Gauss-Jordan with partial pivoting
    double M[16], Inv[16];
    for (int i = 0; i < 16; ++i) M[i] = NH[i];
    eye4(Inv);
    for (int col = 0; col < 4; ++col) {
        int piv = col;
        double best = fabs(M[col * 4 + col]);
        for (int r = col + 1; r < 4; ++r) {
            double v = fabs(M[r * 4 + col]);
            if (v > best) { best = v; piv = r; }
        }
        if (piv != col) {
            for (int j = 0; j < 4; ++j) {
                double t = M[col * 4 + j]; M[col * 4 + j] = M[piv * 4 + j]; M[piv * 4 + j] = t;
                t = Inv[col * 4 + j]; Inv[col * 4 + j] = Inv[piv * 4 + j]; Inv[piv * 4 + j] = t;
            }
        }
        double invd = 1.0 / M[col * 4 + col];
        for (int j = 0; j < 4; ++j) { M[col * 4 + j] *= invd; Inv[col * 4 + j] *= invd; }
        for (int r = 0; r < 4; ++r) {
            if (r == col) continue;
            double f = M[r * 4 + col];
            if (f != 0.0) {
                for (int j = 0; j < 4; ++j) {
                    M[r * 4 + j]   -= f * M[col * 4 + j];
                    Inv[r * 4 + j] -= f * Inv[col * 4 + j];
                }
            }
        }
    }

    // affine_full = inv(new_header) @ vol_affine
    double VA[16];
    for (int i = 0; i < 16; ++i) VA[i] = (double)vol_affine[i];
    double AF[16];
    matmul4(Inv, VA, AF);

    // outputs: affine rows 0..2 (12 floats) then new_header (16 floats)
    for (int i = 0; i < 12; ++i) out[i]      = (float)AF[i];
    for (int i = 0; i < 16; ++i) out[12 + i] = (float)NH[i];
}

extern "C" void kernel_launch(void* const* d_in, const int* in_sizes, int n_in,
                              void* d_out, int out_size, void* d_ws, size_t ws_size,
                              hipStream_t stream) {
    const float* header      = (const float*)d_in[0];
    const float* vol_affine  = (const float*)d_in[1];
    const float* cr          = (const float*)d_in[2];
    const float* normvec     = (const float*)d_in[3];
    const float* translation = (const float*)d_in[4];
    const float* angle       = (const float*)d_in[5];
    const float* scaling     = (const float*)d_in[6];
    float* out = (float*)d_out;

    affine_kernel<<<1, 64, 0, stream>>>(header, vol_affine, cr, normvec,
                                        translation, angle, scaling, out);
}

// Round 4
// 9.719 us; speedup vs baseline: 1.2720x; 1.2720x over previous
//
#include <hip/hip_runtime.h>
#include <math.h>

// Single-thread f32 computation of:
//   T = Ttrans @ T1inv @ T2inv @ T3inv @ T4b3 @ T4b2 @ T4b1 @ T4a @ T3 @ T2 @ T1
//   new_header = T @ header
//   affine = (inv(new_header) @ vol_affine)[:3]
// Output: affine (12 f32) then new_header (16 f32), flat, return order.
// ~1.5 kFLOP total -> launch-overhead bound. f32 + HW transcendentals
// (vs R1's f64 software routines) to cut the serial in-kernel latency chain.
// Accuracy: well-conditioned (header = randn + 4I); f32 err ~1e-5 << thr 0.123.

__device__ inline void matmul4(const float* A, const float* B, float* C) {
    for (int i = 0; i < 4; ++i)
        for (int j = 0; j < 4; ++j) {
            float s = 0.0f;
            for (int k = 0; k < 4; ++k) s = fmaf(A[i*4+k], B[k*4+j], s);
            C[i*4+j] = s;
        }
}

__device__ inline void eye4(float* M) {
    for (int i = 0; i < 16; ++i) M[i] = 0.0f;
    M[0] = M[5] = M[10] = M[15] = 1.0f;
}

__global__ void affine_kernel(const float* __restrict__ header,
                              const float* __restrict__ vol_affine,
                              const float* __restrict__ cr,
                              const float* __restrict__ normvec,
                              const float* __restrict__ translation,
                              const float* __restrict__ angle,
                              const float* __restrict__ scaling,
                              float* __restrict__ out) {
    if (threadIdx.x != 0 || blockIdx.x != 0) return;

    const float PI = 3.14159265358979323846f;

    float n0 = normvec[0], n1 = normvec[1], n2 = normvec[2];
    float nn = sqrtf(fmaf(n0, n0, fmaf(n1, n1, n2 * n2)));
    float nv0 = n0 / nn, nv1 = n1 / nn, nv2 = n2 / nn;
    float norm_xy = sqrtf(fmaf(nv0, nv0, nv1 * nv1));

    bool zero_xy = (norm_xy == 0.0f);
    float safe = zero_xy ? 1.0f : norm_xy;
    float a = zero_xy ? 1.0f : nv0 / safe;
    float b = zero_xy ? 0.0f : nv1 / safe;

    float T1[16], T1inv[16], T2[16], T2inv[16], T3[16], T3inv[16];
    float T4a[16], Ttrans[16];

    eye4(T1);    T1[3]    = -cr[0]; T1[7]    = -cr[1]; T1[11]    = -cr[2];
    eye4(T1inv); T1inv[3] =  cr[0]; T1inv[7] =  cr[1]; T1inv[11] =  cr[2];

    eye4(T2);    T2[0] = a;    T2[1] = b;     T2[4] = -b;    T2[5] = a;
    eye4(T2inv); T2inv[0] = a; T2inv[1] = -b; T2inv[4] = b;  T2inv[5] = a;

    eye4(T3);    T3[0] = nv2;    T3[2] = -norm_xy;    T3[8] = norm_xy;     T3[10] = nv2;
    eye4(T3inv); T3inv[0] = nv2; T3inv[2] = norm_xy;  T3inv[8] = -norm_xy; T3inv[10] = nv2;

    float sxy = __expf(scaling[0] * 0.01f);
    float sz  = __expf(scaling[1] * 0.01f);
    eye4(T4a); T4a[0] = sxy; T4a[5] = sxy; T4a[10] = sz;

    float a0 = angle[0] * (PI / 180.0f);
    float a1 = angle[1] * (PI / 180.0f);
    float a2 = angle[2] * (PI / 180.0f);
    float s0, c0, s1, c1, s2, c2;
    __sincosf(a0, &s0, &c0);
    __sincosf(a1, &s1, &c1);
    __sincosf(a2, &s2, &c2);
    float T4b1_[16], T4b2_[16], T4b3_[16];
    eye4(T4b1_); T4b1_[5] = c0; T4b1_[6] = -s0; T4b1_[9] = s0;  T4b1_[10] = c0;
    eye4(T4b2_); T4b2_[0] = c1; T4b2_[2] = s1;  T4b2_[8] = -s1; T4b2_[10] = c1;
    eye4(T4b3_); T4b3_[0] = c2; T4b3_[1] = -s2; T4b3_[4] = s2;  T4b3_[5] = c2;

    eye4(Ttrans);
    Ttrans[3]  = translation[0];
    Ttrans[7]  = translation[1];
    Ttrans[11] = translation[2];

    float acc[16], tmp[16];
    matmul4(Ttrans, T1inv, acc);
    matmul4(acc, T2inv, tmp);
    matmul4(tmp, T3inv, acc);
    matmul4(acc, T4b3_, tmp);
    matmul4(tmp, T4b2_, acc);
    matmul4(acc, T4b1_, tmp);
    matmul4(tmp, T4a, acc);
    matmul4(acc, T3, tmp);
    matmul4(tmp, T2, acc);
    matmul4(acc, T1, tmp);   // tmp = T

    float H[16];
    for (int i = 0; i < 16; ++i) H[i] = header[i];
    float NH[16];
    matmul4(tmp, H, NH);

    // inv(new_header) via Gauss-Jordan with partial pivoting
    float M[16], Inv[16];
    for (int i = 0; i < 16; ++i) M[i] = NH[i];
    eye4(Inv);
    for (int col = 0; col < 4; ++col) {
        int piv = col;
        float best = fabsf(M[col * 4 + col]);
        for (int r = col + 1; r < 4; ++r) {
            float v = fabsf(M[r * 4 + col]);
            if (v > best) { best = v; piv = r; }
        }
        if (piv != col) {
            for (int j = 0; j < 4; ++j) {
                float t = M[col * 4 + j]; M[col * 4 + j] = M[piv * 4 + j]; M[piv * 4 + j] = t;
                t = Inv[col * 4 + j]; Inv[col * 4 + j] = Inv[piv * 4 + j]; Inv[piv * 4 + j] = t;
            }
        }
        float invd = 1.0f / M[col * 4 + col];
        for (int j = 0; j < 4; ++j) { M[col * 4 + j] *= invd; Inv[col * 4 + j] *= invd; }
        for (int r = 0; r < 4; ++r) {
            if (r == col) continue;
            float f = M[r * 4 + col];
            if (f != 0.0f) {
                for (int j = 0; j < 4; ++j) {
                    M[r * 4 + j]   = fmaf(-f, M[col * 4 + j],   M[r * 4 + j]);
                    Inv[r * 4 + j] = fmaf(-f, Inv[col * 4 + j], Inv[r * 4 + j]);
                }
            }
        }
    }

    float VA[16];
    for (int i = 0; i < 16; ++i) VA[i] = vol_affine[i];
    float AF[16];
    matmul4(Inv, VA, AF);

    for (int i = 0; i < 12; ++i) out[i]      = AF[i];
    for (int i = 0; i < 16; ++i) out[12 + i] = NH[i];
}

extern "C" void kernel_launch(void* const* d_in, const int* in_sizes, int n_in,
                              void* d_out, int out_size, void* d_ws, size_t ws_size,
                              hipStream_t stream) {
    const float* header      = (const float*)d_in[0];
    const float* vol_affine  = (const float*)d_in[1];
    const float* cr          = (const float*)d_in[2];
    const float* normvec     = (const float*)d_in[3];
    const float* translation = (const float*)d_in[4];
    const float* angle       = (const float*)d_in[5];
    const float* scaling     = (const float*)d_in[6];
    float* out = (float*)d_out;

    affine_kernel<<<1, 64, 0, stream>>>(header, vol_affine, cr, normvec,
                                        translation, angle, scaling, out);
}

// Round 5
// 9.535 us; speedup vs baseline: 1.2965x; 1.0192x over previous
//
#include <hip/hip_runtime.h>
#include <math.h>

// Single-thread f32, algebraically reduced:
//   T = Trans(translation+cr) @ M @ Trans(-cr),  M = product of 7 3x3 linear mats
//   (T4a diag folded into Rx by column scaling) -> 6 3x3 matmuls vs 10 4x4.
//   new_header = T @ header  (affine x general)
//   inv(new_header) via branch-free adjugate (well-conditioned: header=randn+4I)
//   affine = (inv @ vol_affine)[:3]
// Output: affine (12 f32) then new_header (16 f32).
// Probe: if dur_us stays ~9.7us, launch floor confirmed -> ROOFLINE.

__device__ inline void mm3(const float* A, const float* B, float* C) {
    for (int i = 0; i < 3; ++i)
        for (int j = 0; j < 3; ++j) {
            float s = A[i*3+0] * B[0*3+j];
            s = fmaf(A[i*3+1], B[1*3+j], s);
            s = fmaf(A[i*3+2], B[2*3+j], s);
            C[i*3+j] = s;
        }
}

__global__ void affine_kernel(const float* __restrict__ header,
                              const float* __restrict__ vol_affine,
                              const float* __restrict__ cr,
                              const float* __restrict__ normvec,
                              const float* __restrict__ translation,
                              const float* __restrict__ angle,
                              const float* __restrict__ scaling,
                              float* __restrict__ out) {
    if (threadIdx.x != 0 || blockIdx.x != 0) return;

    const float PI = 3.14159265358979323846f;

    float n0 = normvec[0], n1 = normvec[1], n2 = normvec[2];
    float nn = sqrtf(fmaf(n0, n0, fmaf(n1, n1, n2 * n2)));
    float nv0 = n0 / nn, nv1 = n1 / nn, nv2 = n2 / nn;
    float nxy = sqrtf(fmaf(nv0, nv0, nv1 * nv1));

    bool zero_xy = (nxy == 0.0f);
    float safe = zero_xy ? 1.0f : nxy;
    float a = zero_xy ? 1.0f : nv0 / safe;
    float b = zero_xy ? 0.0f : nv1 / safe;

    float sxy = __expf(scaling[0] * 0.01f);
    float sz  = __expf(scaling[1] * 0.01f);

    float a0 = angle[0] * (PI / 180.0f);
    float a1 = angle[1] * (PI / 180.0f);
    float a2 = angle[2] * (PI / 180.0f);
    float s0, c0, s1, c1, s2, c2;
    __sincosf(a0, &s0, &c0);
    __sincosf(a1, &s1, &c1);
    __sincosf(a2, &s2, &c2);

    // 3x3 linear blocks (row-major)
    float T23[9]    = { a,  b, 0.0f,  -b,  a, 0.0f,  0.0f, 0.0f, 1.0f };
    float T2inv3[9] = { a, -b, 0.0f,   b,  a, 0.0f,  0.0f, 0.0f, 1.0f };
    float T33[9]    = { nv2, 0.0f, -nxy,  0.0f, 1.0f, 0.0f,  nxy, 0.0f, nv2 };
    float T3inv3[9] = { nv2, 0.0f,  nxy,  0.0f, 1.0f, 0.0f, -nxy, 0.0f, nv2 };
    float Rz[9]     = { c2, -s2, 0.0f,  s2, c2, 0.0f,  0.0f, 0.0f, 1.0f };
    float Ry[9]     = { c1, 0.0f, s1,   0.0f, 1.0f, 0.0f,  -s1, 0.0f, c1 };
    // RxS = Rx(diag-scaled columns): (T4b1 @ T4a)[i][j] = Rx[i][j] * s_j
    float RxS[9]    = { sxy, 0.0f, 0.0f,
                        0.0f, sxy * c0, -sz * s0,
                        0.0f, sxy * s0,  sz * c0 };

    // M = T2inv3 @ T3inv3 @ Rz @ Ry @ RxS @ T33 @ T23  (6 products)
    float A1[9], A2[9], M[9];
    mm3(T2inv3, T3inv3, A1);
    mm3(A1, Rz, A2);
    mm3(A2, Ry, A1);
    mm3(A1, RxS, A2);
    mm3(A2, T33, A1);
    mm3(A1, T23, M);

    // t = translation + cr - M @ cr
    float cr0 = cr[0], cr1 = cr[1], cr2 = cr[2];
    float t0 = translation[0] + cr0 - (fmaf(M[0], cr0, fmaf(M[1], cr1, M[2] * cr2)));
    float t1 = translation[1] + cr1 - (fmaf(M[3], cr0, fmaf(M[4], cr1, M[5] * cr2)));
    float t2 = translation[2] + cr2 - (fmaf(M[6], cr0, fmaf(M[7], cr1, M[8] * cr2)));
    float t[3] = { t0, t1, t2 };

    // new_header = T @ header: rows 0..2 = M@H[0:3,:] + t_i*H[3,:]; row 3 = H[3,:]
    float H[16];
    for (int i = 0; i < 16; ++i) H[i] = header[i];
    float NH[16];
    for (int i = 0; i < 3; ++i)
        for (int j = 0; j < 4; ++j) {
            float s = fmaf(M[i*3+0], H[0*4+j],
                      fmaf(M[i*3+1], H[1*4+j],
                      fmaf(M[i*3+2], H[2*4+j],
                           t[i] * H[3*4+j])));
            NH[i*4+j] = s;
        }
    for (int j = 0; j < 4; ++j) NH[12 + j] = H[12 + j];

    // Branch-free 4x4 inverse via adjugate (2x2 subdeterminant method)
    const float* m = NH;
    float A_ = fmaf(m[0], m[5], -m[4] * m[1]);   // s0 = m00*m11 - m10*m01
    float B_ = fmaf(m[0], m[6], -m[4] * m[2]);   // s1 = m00*m12 - m10*m02
    float C_ = fmaf(m[0], m[7], -m[4] * m[3]);   // s2 = m00*m13 - m10*m03
    float D_ = fmaf(m[1], m[6], -m[5] * m[2]);   // s3 = m01*m12 - m11*m02
    float E_ = fmaf(m[1], m[7], -m[5] * m[3]);   // s4 = m01*m13 - m11*m03
    float F_ = fmaf(m[2], m[7], -m[6] * m[3]);   // s5 = m02*m13 - m12*m03
    float G_ = fmaf(m[8],  m[13], -m[12] * m[9]);  // c5-> m20*m31 - m30*m21
    float Hc = fmaf(m[8],  m[14], -m[12] * m[10]);
    float I_ = fmaf(m[8],  m[15], -m[12] * m[11]);
    float J_ = fmaf(m[9],  m[14], -m[13] * m[10]);
    float K_ = fmaf(m[9],  m[15], -m[13] * m[11]);
    float L_ = fmaf(m[10], m[15], -m[14] * m[11]);

    float det = A_ * L_ - B_ * K_ + C_ * J_ + D_ * I_ - E_ * Hc + F_ * G_;
    float rd = 1.0f / det;

    float Inv[16];
    Inv[0]  = ( m[5] * L_ - m[6] * K_ + m[7] * J_) * rd;
    Inv[1]  = (-m[1] * L_ + m[2] * K_ - m[3] * J_) * rd;
    Inv[2]  = ( m[13] * F_ - m[14] * E_ + m[15] * D_) * rd;
    Inv[3]  = (-m[9]  * F_ + m[10] * E_ - m[11] * D_) * rd;
    Inv[4]  = (-m[4] * L_ + m[6] * I_ - m[7] * Hc) * rd;
    Inv[5]  = ( m[0] * L_ - m[2] * I_ + m[3] * Hc) * rd;
    Inv[6]  = (-m[12] * F_ + m[14] * C_ - m[15] * B_) * rd;
    Inv[7]  = ( m[8]  * F_ - m[10] * C_ + m[11] * B_) * rd;
    Inv[8]  = ( m[4] * K_ - m[5] * I_ + m[7] * G_) * rd;
    Inv[9]  = (-m[0] * K_ + m[1] * I_ - m[3] * G_) * rd;
    Inv[10] = ( m[12] * E_ - m[13] * C_ + m[15] * A_) * rd;
    Inv[11] = (-m[8]  * E_ + m[9]  * C_ - m[11] * A_) * rd;
    Inv[12] = (-m[4] * J_ + m[5] * Hc - m[6] * G_) * rd;
    Inv[13] = ( m[0] * J_ - m[1] * Hc + m[2] * G_) * rd;
    Inv[14] = (-m[12] * D_ + m[13] * B_ - m[14] * A_) * rd;
    Inv[15] = ( m[8]  * D_ - m[9]  * B_ + m[10] * A_) * rd;

    // affine_full = Inv @ vol_affine; output rows 0..2
    float VA[16];
    for (int i = 0; i < 16; ++i) VA[i] = vol_affine[i];
    for (int i = 0; i < 3; ++i)
        for (int j = 0; j < 4; ++j) {
            float s = fmaf(Inv[i*4+0], VA[0*4+j],
                      fmaf(Inv[i*4+1], VA[1*4+j],
                      fmaf(Inv[i*4+2], VA[2*4+j],
                           Inv[i*4+3] * VA[3*4+j])));
            out[i*4+j] = s;
        }
    for (int i = 0; i < 16; ++i) out[12 + i] = NH[i];
}

extern "C" void kernel_launch(void* const* d_in, const int* in_sizes, int n_in,
                              void* d_out, int out_size, void* d_ws, size_t ws_size,
                              hipStream_t stream) {
    const float* header      = (const float*)d_in[0];
    const float* vol_affine  = (const float*)d_in[1];
    const float* cr          = (const float*)d_in[2];
    const float* normvec     = (const float*)d_in[3];
    const float* translation = (const float*)d_in[4];
    const float* angle       = (const float*)d_in[5];
    const float* scaling     = (const float*)d_in[6];
    float* out = (float*)d_out;

    affine_kernel<<<1, 64, 0, stream>>>(header, vol_affine, cr, normvec,
                                        translation, angle, scaling, out);
}